// Round 14
// baseline (181.619 us; speedup 1.0000x reference)
//
#include <hip/hip_runtime.h>
#include <hip/hip_bf16.h>
#include <float.h>

// N=1024, M=1024, D=512, fp32 in/out.
// tanh(q+k) = 1 - 2/(1+exp2(CS*(q+k))), CS=2*log2(e), exp2 factorized:
// eq[n][d]=min(exp2(CS*qp),2^13)*c (c=2^-13 pre-scaled in proj),
// ekT[d][m]=min(exp2(CS*kp),2^13)^T.
// s[n,m] = -2*sum_d Ww[d]/(1+eq*ek) (row-const dropped; softmax shift-inv).
// R19: 8-term rational merge (1 rcp per 8 d via 3-level tree, c^8 scaling).
// R20-R30: score band 54-61us; VALU floor ~33us; occupancy-insensitive ->
// dual-bound: VALU + wave-uniform es/wws ds_read_b128 broadcasts (LDS port).
// R31 (BEST, 170.4): 4m/lane halved broadcasts -> score 54.5.
// R32 (FAILED): direct-global uniform reads did NOT scalarize (SGPR 32->48
// only; per-lane VMEM instead) -> 63.8. REVERTED.
// R33: second notch on the CONFIRMED lever: 8m/lane (2x f4v). Block 256thr
// = 4 waves = dh(4 x 128d), each wave spans 512m (lane owns 8m); es/wws
// broadcasts per eval halved again. 3-wave dump + wave0 reduce (4B lane
// stride, conflict-free, 24KB). Grid (2,256)=512 blocks, LDS 34K ->
// 16 waves/CU. VALU conserved; k L2 traffic unchanged.
// ws: eq 2MB | ekT 2MB | vph/vpl 2MB | Ph/Pl 4MB | rsum 4KB.

#define NROWS 1024
#define DDIM  512
#define MDIM  1024

typedef __attribute__((ext_vector_type(8))) short s8v;    // 8 bf16, 4 VGPR
typedef __attribute__((ext_vector_type(4))) float f4v;
typedef __attribute__((ext_vector_type(2))) float v2f;

__device__ __forceinline__ float bf2f(ushort h) {
    return __uint_as_float(((unsigned)h) << 16);
}
__device__ __forceinline__ ushort2 f2bf2(float a, float b) {   // packed cvt
    __hip_bfloat162 t = __float22bfloat162_rn(float2{a, b});
    union { __hip_bfloat162 v; ushort2 u; } c; c.v = t;
    return c.u;
}
__device__ __forceinline__ void hl2(float a, float b, ushort2& h, ushort2& l) {
    h = f2bf2(a, b);
    l = f2bf2(a - bf2f(h.x), b - bf2f(h.y));
}

// ---------------- K1: fused projection GEMMs (64x32 tile, dbuf, 1 bar/chunk) -
// z=0: eq[n][d]:  A=q,  B=Wq, bias col, exp2+clamp, *c. Block (0,z0) zeroes rsum.
// z=1: ekT[d][m]: A=Wk, B=kk, bias row, exp2+clamp.
// z=2: vpT[d][m]: A=Wv, B=v,  bias row, bf16 h/l out.
__global__ __launch_bounds__(256) void proj_gemm(
    const float* __restrict__ q, const float* __restrict__ kk_,
    const float* __restrict__ v,
    const float* __restrict__ Wq, const float* __restrict__ bq,
    const float* __restrict__ Wk, const float* __restrict__ bk,
    const float* __restrict__ Wv, const float* __restrict__ bv,
    float* __restrict__ eq, float* __restrict__ ekT,
    ushort* __restrict__ vph, ushort* __restrict__ vpl,
    float* __restrict__ rsum, float CS)
{
    __shared__ ushort Ah[2][4096], Al[2][4096], Bh[2][2048], Bl[2][2048];

    const float* A; const float* B; const float* bias;
    int biasRow;
    if (blockIdx.z == 0)      { A = q;   B = Wq;  bias = bq; biasRow = 0; }
    else if (blockIdx.z == 1) { A = Wk;  B = kk_; bias = bk; biasRow = 1; }
    else                      { A = Wv;  B = v;   bias = bv; biasRow = 1; }

    const int bx = blockIdx.x;
    const int bi = (blockIdx.z == 0) ? (bx >> 4) : (bx >> 5);
    const int bj = (blockIdx.z == 0) ? (bx & 15) : (bx & 31);

    const int t    = threadIdx.x;
    const int lane = t & 63;
    const int w    = t >> 6;
    const int lm   = lane & 15;
    const int lq   = lane >> 4;
    const int i0   = bi * 64;
    const int j0   = bj * 32;
    const int mh   = (w >> 1) * 32;
    const int nh   = (w & 1) * 16;

    if (blockIdx.z == 0 && bx == 0) {       // zero rsum for score's atomics
        float4 zz = {0.f, 0.f, 0.f, 0.f};
        *(float4*)&rsum[t * 4] = zz;
    }

    const int sr = t >> 4, sc4 = t & 15;

    float4 pa[4], pb[2];

#define LOAD_CHUNK(KC)                                                         \
    {                                                                          \
        const int k0 = (KC) * 64;                                              \
        _Pragma("unroll")                                                      \
        for (int p = 0; p < 4; ++p)                                            \
            pa[p] = *(const float4*)&A[(size_t)(i0 + sr + p * 16) * DDIM       \
                                       + k0 + sc4 * 4];                        \
        _Pragma("unroll")                                                      \
        for (int p = 0; p < 2; ++p)                                            \
            pb[p] = *(const float4*)&B[(size_t)(j0 + sr + p * 16) * DDIM       \
                                       + k0 + sc4 * 4];                        \
    }

#define WRITE_CHUNK(BUF)                                                       \
    {                                                                          \
        _Pragma("unroll")                                                      \
        for (int p = 0; p < 4; ++p) {                                          \
            int r = sr + p * 16;                                               \
            int ad = r * 64 + (((sc4 >> 1) ^ (r & 7)) << 3) + (sc4 & 1) * 4;   \
            ushort2 h01, l01, h23, l23;                                        \
            hl2(pa[p].x, pa[p].y, h01, l01);                                   \
            hl2(pa[p].z, pa[p].w, h23, l23);                                   \
            ushort4 ha = {h01.x, h01.y, h23.x, h23.y};                         \
            ushort4 la = {l01.x, l01.y, l23.x, l23.y};                         \
            *(ushort4*)&Ah[BUF][ad] = ha;                                      \
            *(ushort4*)&Al[BUF][ad] = la;                                      \
        }                                                                      \
        _Pragma("unroll")                                                      \
        for (int p = 0; p < 2; ++p) {                                          \
            int r = sr + p * 16;                                               \
            int ad = r * 64 + (((sc4 >> 1) ^ (r & 7)) << 3) + (sc4 & 1) * 4;   \
            ushort2 h01, l01, h23, l23;                                        \
            hl2(pb[p].x, pb[p].y, h01, l01);                                   \
            hl2(pb[p].z, pb[p].w, h23, l23);                                   \
            ushort4 hb = {h01.x, h01.y, h23.x, h23.y};                         \
            ushort4 lb = {l01.x, l01.y, l23.x, l23.y};                         \
            *(ushort4*)&Bh[BUF][ad] = hb;                                      \
            *(ushort4*)&Bl[BUF][ad] = lb;                                      \
        }                                                                      \
    }

    f4v acc[2] = {{0.f,0.f,0.f,0.f},{0.f,0.f,0.f,0.f}};

    LOAD_CHUNK(0)
    WRITE_CHUNK(0)
    LOAD_CHUNK(1)
    __syncthreads();

    for (int kc = 0; kc < 8; ++kc) {
        const int buf = kc & 1;
#pragma unroll
        for (int ks = 0; ks < 2; ++ks) {
            const int kb = ks * 4 + lq;
            s8v afh[2], afl[2], bfh, bfl;
#pragma unroll
            for (int g = 0; g < 2; ++g) {
                int ra = mh + g * 16 + lm;
                int aa = ra * 64 + ((kb ^ (ra & 7)) << 3);
                afh[g] = *(const s8v*)&Ah[buf][aa];
                afl[g] = *(const s8v*)&Al[buf][aa];
            }
            {
                int rb = nh + lm;
                int ab = rb * 64 + ((kb ^ (rb & 7)) << 3);
                bfh = *(const s8v*)&Bh[buf][ab];
                bfl = *(const s8v*)&Bl[buf][ab];
            }
#pragma unroll
            for (int mi = 0; mi < 2; ++mi) {
                acc[mi] = __builtin_amdgcn_mfma_f32_16x16x32_bf16(
                    afh[mi], bfh, acc[mi], 0, 0, 0);
                acc[mi] = __builtin_amdgcn_mfma_f32_16x16x32_bf16(
                    afh[mi], bfl, acc[mi], 0, 0, 0);
                acc[mi] = __builtin_amdgcn_mfma_f32_16x16x32_bf16(
                    afl[mi], bfh, acc[mi], 0, 0, 0);
            }
        }
        if (kc < 7) {
            WRITE_CHUNK(buf ^ 1)
        }
        if (kc < 6) {
            LOAD_CHUNK(kc + 2)
        }
        __syncthreads();
    }

    const float CLAMP = 8192.0f;   // 2^13: scaled 8-term den < 2^104
    const float SCw   = 1.220703125e-4f;   // c = 2^-13 (pre-scale eq)
#pragma unroll
    for (int mi = 0; mi < 2; ++mi) {
#pragma unroll
        for (int p = 0; p < 4; ++p) {
            int row = i0 + mh + mi * 16 + lq * 4 + p;
            int col = j0 + nh + lm;
            float val = acc[mi][p] + (biasRow ? bias[row] : bias[col]);
            if (blockIdx.z == 0) {
                eq[(size_t)row * 512 + col] =
                    fminf(__builtin_amdgcn_exp2f(val * CS), CLAMP) * SCw;
            } else if (blockIdx.z == 1) {
                ekT[(size_t)row * 1024 + col] =
                    fminf(__builtin_amdgcn_exp2f(val * CS), CLAMP);
            } else {
                ushort2 h2 = f2bf2(val, val);
                vph[(size_t)row * 1024 + col] = h2.x;
                ushort2 l2 = f2bf2(val - bf2f(h2.x), 0.f);
                vpl[(size_t)row * 1024 + col] = l2.x;
            }
        }
    }
#undef LOAD_CHUNK
#undef WRITE_CHUNK
}

// ---------------- K2: score+softmax fused (8m/lane, 4-way d-split) -----------
// P[n][m] = mask ? exp2(C2 * sum_{d=0..511} Ww[d]/(1+eq*ek)) : 0 -> bf16 h/l
// Block 256 thr = 4 waves = dh(0..3, 128d quarter); each wave spans 512m
// (lane owns 8 m = f4v lo+hi); all 4 n from shared es. es/wws broadcast
// reads per eval HALVED vs R31 (the confirmed co-limiting pipe). dh>0 dumps
// 32 comps to red (4B lane stride, conflict-free), 1 barrier, dh=0 sums +
// fused mask/exp2/bf16/rsum epilogue. Grid (2,256) = 512 blocks, LDS 34KB
// -> 4 blocks/CU = 16 waves/CU.

#define TREE16(KL0,KL1,KL2,KL3,KL4,KL5,KL6,KL7,                                \
               KH0,KH1,KH2,KH3,KH4,KH5,KH6,KH7,DCQ)                            \
    {                                                                          \
        float4 wgA = *(const float4*)&wws[(DCQ)];                              \
        float4 wgB = *(const float4*)&wws[(DCQ) + 4];                          \
        _Pragma("unroll")                                                      \
        for (int nn = 0; nn < 4; ++nn) {                                       \
            float4 egA = *(const float4*)&es[nn * 512 + (DCQ)];                \
            float4 egB = *(const float4*)&es[nn * 512 + (DCQ) + 4];            \
            f4v eA0 = {egA.x, egA.x, egA.x, egA.x};                            \
            f4v eA1 = {egA.y, egA.y, egA.y, egA.y};                            \
            f4v eA2 = {egA.z, egA.z, egA.z, egA.z};                            \
            f4v eA3 = {egA.w, egA.w, egA.w, egA.w};                            \
            f4v eB0 = {egB.x, egB.x, egB.x, egB.x};                            \
            f4v eB1 = {egB.y, egB.y, egB.y, egB.y};                            \
            f4v eB2 = {egB.z, egB.z, egB.z, egB.z};                            \
            f4v eB3 = {egB.w, egB.w, egB.w, egB.w};                            \
            f4v wA0 = {wgA.x, wgA.x, wgA.x, wgA.x};                            \
            f4v wA1 = {wgA.y, wgA.y, wgA.y, wgA.y};                            \
            f4v wA2 = {wgA.z, wgA.z, wgA.z, wgA.z};                            \
            f4v wA3 = {wgA.w, wgA.w, wgA.w, wgA.w};                            \
            f4v wB0 = {wgB.x, wgB.x, wgB.x, wgB.x};                            \
            f4v wB1 = {wgB.y, wgB.y, wgB.y, wgB.y};                            \
            f4v wB2 = {wgB.z, wgB.z, wgB.z, wgB.z};                            \
            f4v wB3 = {wgB.w, wgB.w, wgB.w, wgB.w};                            \
            /* lo half (m 0..3) */                                             \
            {                                                                  \
                f4v A0 = __builtin_elementwise_fma(KL0, eA0, cc4);             \
                f4v A1 = __builtin_elementwise_fma(KL1, eA1, cc4);             \
                f4v A2 = __builtin_elementwise_fma(KL2, eA2, cc4);             \
                f4v A3 = __builtin_elementwise_fma(KL3, eA3, cc4);             \
                f4v A4 = __builtin_elementwise_fma(KL4, eB0, cc4);             \
                f4v A5 = __builtin_elementwise_fma(KL5, eB1, cc4);             \
                f4v A6 = __builtin_elementwise_fma(KL6, eB2, cc4);             \
                f4v A7 = __builtin_elementwise_fma(KL7, eB3, cc4);             \
                f4v n01 = __builtin_elementwise_fma(wA1, A0, wA0 * A1);        \
                f4v d01 = A0 * A1;                                             \
                f4v n23 = __builtin_elementwise_fma(wA3, A2, wA2 * A3);        \
                f4v d23 = A2 * A3;                                             \
                f4v n45 = __builtin_elementwise_fma(wB1, A4, wB0 * A5);        \
                f4v d45 = A4 * A5;                                             \
                f4v n67 = __builtin_elementwise_fma(wB3, A6, wB2 * A7);        \
                f4v d67 = A6 * A7;                                             \
                f4v nA = __builtin_elementwise_fma(n01, d23, n23 * d01);       \
                f4v dA = d01 * d23;                                            \
                f4v nB = __builtin_elementwise_fma(n45, d67, n67 * d45);       \
                f4v dB = d45 * d67;                                            \
                f4v num = __builtin_elementwise_fma(nA, dB, nB * dA);          \
                f4v den = dA * dB;                                             \
                f4v r = {__builtin_amdgcn_rcpf(den.x),                         \
                         __builtin_amdgcn_rcpf(den.y),                         \
                         __builtin_amdgcn_rcpf(den.z),                         \
                         __builtin_amdgcn_rcpf(den.w)};                        \
                accL[nn] = __builtin_elementwise_fma(num, r, accL[nn]);        \
            }                                                                  \
            /* hi half (m 4..7) */                                             \
            {                                                                  \
                f4v A0 = __builtin_elementwise_fma(KH0, eA0, cc4);             \
                f4v A1 = __builtin_elementwise_fma(KH1, eA1, cc4);             \
                f4v A2 = __builtin_elementwise_fma(KH2, eA2, cc4);             \
                f4v A3 = __builtin_elementwise_fma(KH3, eA3, cc4);             \
                f4v A4 = __builtin_elementwise_fma(KH4, eB0, cc4);             \
                f4v A5 = __builtin_elementwise_fma(KH5, eB1, cc4);             \
                f4v A6 = __builtin_elementwise_fma(KH6, eB2, cc4);             \
                f4v A7 = __builtin_elementwise_fma(KH7, eB3, cc4);             \
                f4v n01 = __builtin_elementwise_fma(wA1, A0, wA0 * A1);        \
                f4v d01 = A0 * A1;                                             \
                f4v n23 = __builtin_elementwise_fma(wA3, A2, wA2 * A3);        \
                f4v d23 = A2 * A3;                                             \
                f4v n45 = __builtin_elementwise_fma(wB1, A4, wB0 * A5);        \
                f4v d45 = A4 * A5;                                             \
                f4v n67 = __builtin_elementwise_fma(wB3, A6, wB2 * A7);        \
                f4v d67 = A6 * A7;                                             \
                f4v nA = __builtin_elementwise_fma(n01, d23, n23 * d01);       \
                f4v dA = d01 * d23;                                            \
                f4v nB = __builtin_elementwise_fma(n45, d67, n67 * d45);       \
                f4v dB = d45 * d67;                                            \
                f4v num = __builtin_elementwise_fma(nA, dB, nB * dA);          \
                f4v den = dA * dB;                                             \
                f4v r = {__builtin_amdgcn_rcpf(den.x),                         \
                         __builtin_amdgcn_rcpf(den.y),                         \
                         __builtin_amdgcn_rcpf(den.z),                         \
                         __builtin_amdgcn_rcpf(den.w)};                        \
                accH[nn] = __builtin_elementwise_fma(num, r, accH[nn]);        \
            }                                                                  \
        }                                                                      \
    }

#define LOADK(DST_L, DST_H, ROWPTR)                                            \
    DST_L = *(const f4v*)(ROWPTR);                                             \
    DST_H = *(const f4v*)((ROWPTR) + 4);

__global__ __launch_bounds__(256) void score_kernel(const float* __restrict__ eq,
                                                    const float* __restrict__ ekT,
                                                    const float* __restrict__ Ww,
                                                    const int* __restrict__ mask,
                                                    ushort* __restrict__ Ph,
                                                    ushort* __restrict__ Pl,
                                                    float* __restrict__ rsum)
{
    __shared__ __align__(16) float es[4 * 512];       // 8 KB (pre-scaled eq)
    __shared__ __align__(16) float wws[512];          // 2 KB (scaled)
    __shared__ __align__(16) float red[3 * 32 * 64];  // 24 KB [wave][comp][lane]
    const int t    = threadIdx.x;
    const int lane = t & 63;
    const int w    = t >> 6;                 // 0..3 = dh (d-quarter)
    const int mw   = blockIdx.x * 512;       // block's m-base (512 cols)
    const int n0   = blockIdx.y * 4;
    const int db   = w * 128;                // wave's d-base

    const float SC = 1.220703125e-4f;        // c = 2^-13

    // stage es: 4n x 512d = 512 float4-slots; 256 threads x 2
#pragma unroll
    for (int p = 0; p < 2; ++p) {
        int idx = t + p * 256;
        int nl = idx >> 7, c4 = idx & 127;
        *(float4*)&es[nl * 512 + c4 * 4] =
            *(const float4*)&eq[(size_t)(n0 + nl) * DDIM + c4 * 4];
    }
    wws[t]       = Ww[t] * SC;
    wws[t + 256] = Ww[t + 256] * SC;

    // per-lane k stream over d-quarter [db, db+128); lane owns 8 m
    const float* gk = ekT + (size_t)db * MDIM + mw + lane * 8;

    f4v aL0, aH0, aL1, aH1, aL2, aH2, aL3, aH3;
    f4v aL4, aH4, aL5, aH5, aL6, aH6, aL7, aH7;
    LOADK(aL0, aH0, gk + (size_t)0 * MDIM)
    LOADK(aL1, aH1, gk + (size_t)1 * MDIM)
    LOADK(aL2, aH2, gk + (size_t)2 * MDIM)
    LOADK(aL3, aH3, gk + (size_t)3 * MDIM)
    LOADK(aL4, aH4, gk + (size_t)4 * MDIM)
    LOADK(aL5, aH5, gk + (size_t)5 * MDIM)
    LOADK(aL6, aH6, gk + (size_t)6 * MDIM)
    LOADK(aL7, aH7, gk + (size_t)7 * MDIM)

    __syncthreads();   // es/wws visible

    f4v accL[4] = {}, accH[4] = {};
    const f4v cc4 = {1.220703125e-4f, 1.220703125e-4f,
                     1.220703125e-4f, 1.220703125e-4f};   // {c,c,c,c}

    for (int dc = 0; dc < 128; dc += 16) {
        const float* g8 = gk + (size_t)(dc + 8) * MDIM;
        f4v bL0, bH0, bL1, bH1, bL2, bH2, bL3, bH3;
        f4v bL4, bH4, bL5, bH5, bL6, bH6, bL7, bH7;
        LOADK(bL0, bH0, g8 + (size_t)0 * MDIM)
        LOADK(bL1, bH1, g8 + (size_t)1 * MDIM)
        LOADK(bL2, bH2, g8 + (size_t)2 * MDIM)
        LOADK(bL3, bH3, g8 + (size_t)3 * MDIM)
        LOADK(bL4, bH4, g8 + (size_t)4 * MDIM)
        LOADK(bL5, bH5, g8 + (size_t)5 * MDIM)
        LOADK(bL6, bH6, g8 + (size_t)6 * MDIM)
        LOADK(bL7, bH7, g8 + (size_t)7 * MDIM)

        TREE16(aL0, aL1, aL2, aL3, aL4, aL5, aL6, aL7,
               aH0, aH1, aH2, aH3, aH4, aH5, aH6, aH7, db + dc)

        if (dc + 16 < 128) {
            const float* g16 = gk + (size_t)(dc + 16) * MDIM;
            LOADK(aL0, aH0, g16 + (size_t)0 * MDIM)
            LOADK(aL1, aH1, g16 + (size_t)1 * MDIM)
            LOADK(aL2, aH2, g16 + (size_t)2 * MDIM)
            LOADK(aL3, aH3, g16 + (size_t)3 * MDIM)
            LOADK(aL4, aH4, g16 + (size_t)4 * MDIM)
            LOADK(aL5, aH5, g16 + (size_t)5 * MDIM)
            LOADK(aL6, aH6, g16 + (size_t)6 * MDIM)
            LOADK(aL7, aH7, g16 + (size_t)7 * MDIM)
        }

        TREE16(bL0, bL1, bL2, bL3, bL4, bL5, bL6, bL7,
               bH0, bH1, bH2, bH3, bH4, bH5, bH6, bH7, db + dc + 8)
    }

    // d-quarter reduction: waves 1..3 dump 32 comps (4B lane stride)
    if (w > 0) {
        float* rb = &red[((w - 1) * 32) * 64 + lane];
#pragma unroll
        for (int nn = 0; nn < 4; ++nn) {
            rb[(nn * 8 + 0) * 64] = accL[nn].x;
            rb[(nn * 8 + 1) * 64] = accL[nn].y;
            rb[(nn * 8 + 2) * 64] = accL[nn].z;
            rb[(nn * 8 + 3) * 64] = accL[nn].w;
            rb[(nn * 8 + 4) * 64] = accH[nn].x;
            rb[(nn * 8 + 5) * 64] = accH[nn].y;
            rb[(nn * 8 + 6) * 64] = accH[nn].z;
            rb[(nn * 8 + 7) * 64] = accH[nn].w;
        }
    }
    __syncthreads();
    if (w == 0) {
#pragma unroll
        for (int i = 0; i < 3; ++i) {
            const float* rb = &red[(i * 32) * 64 + lane];
#pragma unroll
            for (int nn = 0; nn < 4; ++nn) {
                accL[nn].x += rb[(nn * 8 + 0) * 64];
                accL[nn].y += rb[(nn * 8 + 1) * 64];
                accL[nn].z += rb[(nn * 8 + 2) * 64];
                accL[nn].w += rb[(nn * 8 + 3) * 64];
                accH[nn].x += rb[(nn * 8 + 4) * 64];
                accH[nn].y += rb[(nn * 8 + 5) * 64];
                accH[nn].z += rb[(nn * 8 + 6) * 64];
                accH[nn].w += rb[(nn * 8 + 7) * 64];
            }
        }

        // fused softmax epilogue: mask + exp2 + bf16 h/l + row partials
        const float C2 = -2.8853900817779268f;   // -2*log2(e)
        const int m = mw + lane * 8;
        float rs[4];
#pragma unroll
        for (int nn = 0; nn < 4; ++nn) {
            int n = n0 + nn;
            int4 mkL = *(const int4*)&mask[(size_t)n * MDIM + m];
            int4 mkH = *(const int4*)&mask[(size_t)n * MDIM + m + 4];
            float p0 = mkL.x ? __builtin_amdgcn_exp2f(accL[nn].x * C2) : 0.f;
            float p1 = mkL.y ? __builtin_amdgcn_exp2f(accL[nn].y * C2) : 0.f;
            float p2 = mkL.z ? __builtin_amdgcn_exp2f(accL[nn].z * C2) : 0.f;
            float p3 = mkL.w ? __builtin_amdgcn_exp2f(accL[nn].w * C2) : 0.f;
            float p4 = mkH.x ? __builtin_amdgcn_exp2f(accH[nn].x * C2) : 0.f;
            float p5 = mkH.y ? __builtin_amdgcn_exp2f(accH[nn].y * C2) : 0.f;
            float p6 = mkH.z ? __builtin_amdgcn_exp2f(accH[nn].z * C2) : 0.f;
            float p7 = mkH.w ? __builtin_amdgcn_exp2f(accH[nn].w * C2) : 0.f;
            ushort2 h01, l01, h23, l23, h45, l45, h67, l67;
            hl2(p0, p1, h01, l01);
            hl2(p2, p3, h23, l23);
            hl2(p4, p5, h45, l45);
            hl2(p6, p7, h67, l67);
            ushort4 hvL = {h01.x, h01.y, h23.x, h23.y};
            ushort4 lvL = {l01.x, l01.y, l23.x, l23.y};
            ushort4 hvH = {h45.x, h45.y, h67.x, h67.y};
            ushort4 lvH = {l45.x, l45.y, l67.x, l67.y};
            *(ushort4*)&Ph[(size_t)n * MDIM + m]     = hvL;
            *(ushort4*)&Pl[(size_t)n * MDIM + m]     = lvL;
            *(ushort4*)&Ph[(size_t)n * MDIM + m + 4] = hvH;
            *(ushort4*)&Pl[(size_t)n * MDIM + m + 4] = lvH;
            rs[nn] = ((p0 + p1) + (p2 + p3)) + ((p4 + p5) + (p6 + p7));
        }
#pragma unroll
        for (int off = 32; off; off >>= 1) {
            rs[0] += __shfl_xor(rs[0], off);
            rs[1] += __shfl_xor(rs[1], off);
            rs[2] += __shfl_xor(rs[2], off);
            rs[3] += __shfl_xor(rs[3], off);
        }
        if (lane == 0) {
#pragma unroll
            for (int nn = 0; nn < 4; ++nn)
                atomicAdd(&rsum[n0 + nn], rs[nn]);
        }
    }
}

// ---------------- K3: context MFMA (m-split x4 + LDS reduce) -----------------
// out[n][d] = (sum_m P[n][m]*vpT[d][m]) * rcp(rsum[n])
// grid (32,64) = 2048 blocks = 8/CU. Wave w sums m in [w*256,(w+1)*256);
// partials LDS-reduced by wave 0.
__global__ __launch_bounds__(256) void ctx_gemm(const ushort* __restrict__ Ph,
                                                const ushort* __restrict__ Pl,
                                                const ushort* __restrict__ vph,
                                                const ushort* __restrict__ vpl,
                                                const float* __restrict__ rsum,
                                                float* __restrict__ out)
{
    __shared__ __align__(16) float red[3 * 64 * 4];   // 3 KB
    const int t    = threadIdx.x;
    const int lane = t & 63;
    const int w    = t >> 6;
    const int lm   = lane & 15;
    const int lq   = lane >> 4;
    const int d0   = blockIdx.x * 16;
    const int n0   = blockIdx.y * 16;
    const int mb   = w * 256;

    const ushort* pAh = Ph  + (size_t)(n0 + lm) * MDIM + mb + lq * 8;
    const ushort* pAl = Pl  + (size_t)(n0 + lm) * MDIM + mb + lq * 8;
    const ushort* pBh = vph + (size_t)(d0 + lm) * MDIM + mb + lq * 8;
    const ushort* pBl = vpl + (size_t)(d0 + lm) * MDIM + mb + lq * 8;

    f4v acc = {0.f, 0.f, 0.f, 0.f};
#pragma unroll 4
    for (int m0 = 0; m0 < 256; m0 += 32) {
        s8v ah = *(const s8v*)(pAh + m0);
        s8v al = *(const s8v*)(pAl + m0);
        s8v bh = *(const s8v*)(pBh + m0);
        s8v bl = *(const s8v*)(pBl + m0);
        acc = __builtin_amdgcn_mfma_f32_16x16x32_bf16(ah, bh, acc, 0, 0, 0);
        acc = __builtin_amdgcn_mfma_f32_16x16x32_bf16(ah, bl, acc, 0, 0, 0);
        acc = __builtin_amdgcn_mfma_f32_16x16x32_bf16(al, bh, acc, 0, 0, 0);
    }

    if (w > 0) *(f4v*)&red[((w - 1) * 64 + lane) * 4] = acc;
    __syncthreads();
    if (w == 0) {
#pragma unroll
        for (int i = 0; i < 3; ++i)
            acc += *(const f4v*)&red[(i * 64 + lane) * 4];
#pragma unroll
        for (int p = 0; p < 4; ++p) {
            int nrow = n0 + lq * 4 + p;
            float inv = __builtin_amdgcn_rcpf(rsum[nrow]);
            out[(size_t)nrow * DDIM + d0 + lm] = acc[p] * inv;
        }
    }
}

extern "C" void kernel_launch(void* const* d_in, const int* in_sizes, int n_in,
                              void* d_out, int out_size, void* d_ws, size_t ws_size,
                              hipStream_t stream)
{
    const float* q    = (const float*)d_in[0];
    const float* k    = (const float*)d_in[1];
    const float* v    = (const float*)d_in[2];
    const int*   mask = (const int*)d_in[3];
    const float* Wq   = (const float*)d_in[4];
    const float* bq   = (const float*)d_in[5];
    const float* Wk   = (const float*)d_in[6];
    const float* bk   = (const float*)d_in[7];
    const float* Wv   = (const float*)d_in[8];
    const float* bv   = (const float*)d_in[9];
    const float* Ww   = (const float*)d_in[10];
    // d_in[11] (bw) cancels under softmax.

    float* ws    = (float*)d_ws;
    float* eq    = ws;                       // 512K floats [1024 n][512 d]
    float* ekT   = ws + 524288;              // 512K [512 d][1024 m]
    ushort* vph  = (ushort*)(ws + 1048576);  // 1M ushorts [512 d][1024 m]
    ushort* vpl  = (ushort*)(ws + 1310720);  // 1M ushorts
    ushort* Ph   = (ushort*)(ws + 1572864);  // 1M ushorts [1024 n][1024 m]
    ushort* Pl   = (ushort*)(ws + 2097152);  // 1M ushorts
    float* rsum  = ws + 2621440;             // 1K floats
    float* out   = (float*)d_out;

    const float CS = 2.8853900817779268f;    // 2*log2(e)

    proj_gemm<<<dim3(256, 1, 3), dim3(256), 0, stream>>>(q, k, v, Wq, bq, Wk, bk,
                                                         Wv, bv, eq, ekT,
                                                         vph, vpl, rsum, CS);
    score_kernel<<<dim3(2, 256), dim3(256), 0, stream>>>(eq, ekT, Ww, mask,
                                                         Ph, Pl, rsum);
    ctx_gemm<<<dim3(32, 64), dim3(256), 0, stream>>>(Ph, Pl, vph, vpl, rsum, out);
}

// Round 15
// 167.913 us; speedup vs baseline: 1.0816x; 1.0816x over previous
//
#include <hip/hip_runtime.h>
#include <hip/hip_bf16.h>
#include <float.h>

// N=1024, M=1024, D=512, fp32 in/out.
// tanh(q+k) = 1 - 2/(1+exp2(CS*(q+k))), CS=2*log2(e), exp2 factorized:
// eq[n][d]=min(exp2(CS*qp),2^13)*c (c=2^-13 pre-scaled in proj),
// ekT[d][m]=min(exp2(CS*kp),2^13)^T.
// s[n,m] = -2*sum_d Ww[d]/(1+eq*ek) (row-const dropped; softmax shift-inv).
// R19: 8-term rational merge (1 rcp per 8 d via 3-level tree, c^8 scaling).
// R20-R30: score band 54-61us; VALU floor ~33us (conserved in EVERY variant);
// occupancy-insensitive -> dual-bound: VALU + wave-uniform es/wws
// ds_read_b128 broadcasts (LDS port).
// R31 (BEST, 170.4 total / score 54.5): 4m/lane halved broadcasts.
// R32 (FAILED, 63.8): direct-global uniform reads didn't scalarize.
// R33 (FAILED, 68.8): 8m/lane -> VGPR 160 -> 1 block/CU, occupancy 9%.
// Second notch of the broadcast lever is blocked by a VGPR wall (needs >=128
// k-regs by construction). R34: REVERT to R31 exactly - lock in the best.
// Budget at R31: ~33us VALU (conserved) + ~8-17us residual broadcast +
// overlap loss = 54.5; proj+ctx ~20-25us (never in top-5, <48us each);
// remainder of total = fixed per-dispatch harness overhead.
// ws: eq 2MB | ekT 2MB | vph/vpl 2MB | Ph/Pl 4MB | rsum 4KB.

#define NROWS 1024
#define DDIM  512
#define MDIM  1024

typedef __attribute__((ext_vector_type(8))) short s8v;    // 8 bf16, 4 VGPR
typedef __attribute__((ext_vector_type(4))) float f4v;
typedef __attribute__((ext_vector_type(2))) float v2f;

__device__ __forceinline__ float bf2f(ushort h) {
    return __uint_as_float(((unsigned)h) << 16);
}
__device__ __forceinline__ ushort2 f2bf2(float a, float b) {   // packed cvt
    __hip_bfloat162 t = __float22bfloat162_rn(float2{a, b});
    union { __hip_bfloat162 v; ushort2 u; } c; c.v = t;
    return c.u;
}
__device__ __forceinline__ void hl2(float a, float b, ushort2& h, ushort2& l) {
    h = f2bf2(a, b);
    l = f2bf2(a - bf2f(h.x), b - bf2f(h.y));
}

// ---------------- K1: fused projection GEMMs (64x32 tile, dbuf, 1 bar/chunk) -
// z=0: eq[n][d]:  A=q,  B=Wq, bias col, exp2+clamp, *c. Block (0,z0) zeroes rsum.
// z=1: ekT[d][m]: A=Wk, B=kk, bias row, exp2+clamp.
// z=2: vpT[d][m]: A=Wv, B=v,  bias row, bf16 h/l out.
__global__ __launch_bounds__(256) void proj_gemm(
    const float* __restrict__ q, const float* __restrict__ kk_,
    const float* __restrict__ v,
    const float* __restrict__ Wq, const float* __restrict__ bq,
    const float* __restrict__ Wk, const float* __restrict__ bk,
    const float* __restrict__ Wv, const float* __restrict__ bv,
    float* __restrict__ eq, float* __restrict__ ekT,
    ushort* __restrict__ vph, ushort* __restrict__ vpl,
    float* __restrict__ rsum, float CS)
{
    __shared__ ushort Ah[2][4096], Al[2][4096], Bh[2][2048], Bl[2][2048];

    const float* A; const float* B; const float* bias;
    int biasRow;
    if (blockIdx.z == 0)      { A = q;   B = Wq;  bias = bq; biasRow = 0; }
    else if (blockIdx.z == 1) { A = Wk;  B = kk_; bias = bk; biasRow = 1; }
    else                      { A = Wv;  B = v;   bias = bv; biasRow = 1; }

    const int bx = blockIdx.x;
    const int bi = (blockIdx.z == 0) ? (bx >> 4) : (bx >> 5);
    const int bj = (blockIdx.z == 0) ? (bx & 15) : (bx & 31);

    const int t    = threadIdx.x;
    const int lane = t & 63;
    const int w    = t >> 6;
    const int lm   = lane & 15;
    const int lq   = lane >> 4;
    const int i0   = bi * 64;
    const int j0   = bj * 32;
    const int mh   = (w >> 1) * 32;
    const int nh   = (w & 1) * 16;

    if (blockIdx.z == 0 && bx == 0) {       // zero rsum for score's atomics
        float4 zz = {0.f, 0.f, 0.f, 0.f};
        *(float4*)&rsum[t * 4] = zz;
    }

    const int sr = t >> 4, sc4 = t & 15;

    float4 pa[4], pb[2];

#define LOAD_CHUNK(KC)                                                         \
    {                                                                          \
        const int k0 = (KC) * 64;                                              \
        _Pragma("unroll")                                                      \
        for (int p = 0; p < 4; ++p)                                            \
            pa[p] = *(const float4*)&A[(size_t)(i0 + sr + p * 16) * DDIM       \
                                       + k0 + sc4 * 4];                        \
        _Pragma("unroll")                                                      \
        for (int p = 0; p < 2; ++p)                                            \
            pb[p] = *(const float4*)&B[(size_t)(j0 + sr + p * 16) * DDIM       \
                                       + k0 + sc4 * 4];                        \
    }

#define WRITE_CHUNK(BUF)                                                       \
    {                                                                          \
        _Pragma("unroll")                                                      \
        for (int p = 0; p < 4; ++p) {                                          \
            int r = sr + p * 16;                                               \
            int ad = r * 64 + (((sc4 >> 1) ^ (r & 7)) << 3) + (sc4 & 1) * 4;   \
            ushort2 h01, l01, h23, l23;                                        \
            hl2(pa[p].x, pa[p].y, h01, l01);                                   \
            hl2(pa[p].z, pa[p].w, h23, l23);                                   \
            ushort4 ha = {h01.x, h01.y, h23.x, h23.y};                         \
            ushort4 la = {l01.x, l01.y, l23.x, l23.y};                         \
            *(ushort4*)&Ah[BUF][ad] = ha;                                      \
            *(ushort4*)&Al[BUF][ad] = la;                                      \
        }                                                                      \
        _Pragma("unroll")                                                      \
        for (int p = 0; p < 2; ++p) {                                          \
            int r = sr + p * 16;                                               \
            int ad = r * 64 + (((sc4 >> 1) ^ (r & 7)) << 3) + (sc4 & 1) * 4;   \
            ushort2 h01, l01, h23, l23;                                        \
            hl2(pb[p].x, pb[p].y, h01, l01);                                   \
            hl2(pb[p].z, pb[p].w, h23, l23);                                   \
            ushort4 hb = {h01.x, h01.y, h23.x, h23.y};                         \
            ushort4 lb = {l01.x, l01.y, l23.x, l23.y};                         \
            *(ushort4*)&Bh[BUF][ad] = hb;                                      \
            *(ushort4*)&Bl[BUF][ad] = lb;                                      \
        }                                                                      \
    }

    f4v acc[2] = {{0.f,0.f,0.f,0.f},{0.f,0.f,0.f,0.f}};

    LOAD_CHUNK(0)
    WRITE_CHUNK(0)
    LOAD_CHUNK(1)
    __syncthreads();

    for (int kc = 0; kc < 8; ++kc) {
        const int buf = kc & 1;
#pragma unroll
        for (int ks = 0; ks < 2; ++ks) {
            const int kb = ks * 4 + lq;
            s8v afh[2], afl[2], bfh, bfl;
#pragma unroll
            for (int g = 0; g < 2; ++g) {
                int ra = mh + g * 16 + lm;
                int aa = ra * 64 + ((kb ^ (ra & 7)) << 3);
                afh[g] = *(const s8v*)&Ah[buf][aa];
                afl[g] = *(const s8v*)&Al[buf][aa];
            }
            {
                int rb = nh + lm;
                int ab = rb * 64 + ((kb ^ (rb & 7)) << 3);
                bfh = *(const s8v*)&Bh[buf][ab];
                bfl = *(const s8v*)&Bl[buf][ab];
            }
#pragma unroll
            for (int mi = 0; mi < 2; ++mi) {
                acc[mi] = __builtin_amdgcn_mfma_f32_16x16x32_bf16(
                    afh[mi], bfh, acc[mi], 0, 0, 0);
                acc[mi] = __builtin_amdgcn_mfma_f32_16x16x32_bf16(
                    afh[mi], bfl, acc[mi], 0, 0, 0);
                acc[mi] = __builtin_amdgcn_mfma_f32_16x16x32_bf16(
                    afl[mi], bfh, acc[mi], 0, 0, 0);
            }
        }
        if (kc < 7) {
            WRITE_CHUNK(buf ^ 1)
        }
        if (kc < 6) {
            LOAD_CHUNK(kc + 2)
        }
        __syncthreads();
    }

    const float CLAMP = 8192.0f;   // 2^13: scaled 8-term den < 2^104
    const float SCw   = 1.220703125e-4f;   // c = 2^-13 (pre-scale eq)
#pragma unroll
    for (int mi = 0; mi < 2; ++mi) {
#pragma unroll
        for (int p = 0; p < 4; ++p) {
            int row = i0 + mh + mi * 16 + lq * 4 + p;
            int col = j0 + nh + lm;
            float val = acc[mi][p] + (biasRow ? bias[row] : bias[col]);
            if (blockIdx.z == 0) {
                eq[(size_t)row * 512 + col] =
                    fminf(__builtin_amdgcn_exp2f(val * CS), CLAMP) * SCw;
            } else if (blockIdx.z == 1) {
                ekT[(size_t)row * 1024 + col] =
                    fminf(__builtin_amdgcn_exp2f(val * CS), CLAMP);
            } else {
                ushort2 h2 = f2bf2(val, val);
                vph[(size_t)row * 1024 + col] = h2.x;
                ushort2 l2 = f2bf2(val - bf2f(h2.x), 0.f);
                vpl[(size_t)row * 1024 + col] = l2.x;
            }
        }
    }
#undef LOAD_CHUNK
#undef WRITE_CHUNK
}

// ---------------- K2: score+softmax fused (4m/lane f4v, 2-way d-split) -------
// P[n][m] = mask ? exp2(C2 * sum_{d=0..511} Ww[d]/(1+eq*ek)) : 0 -> bf16 h/l
// Block 256 thr = 4 waves = dh(0..1, 256d half) x mg(0..1, 256 m-cols); lane
// owns 4 m (f4v) -> es/wws broadcast reads per eval HALVED vs R30 (the
// identified LDS-port co-bound). All 4 n from shared es (k-reuse 4:1; L2
// traffic unchanged). Barrier-free f4v engine; dh=1 dumps acc to red
// (4B lane stride, conflict-free), 1 barrier, dh=0 sums + fused epilogue.
// Grid (2,256) = 512 blocks = 8 waves/CU. LDS: es 8K + wws 2K + red 8K.

#define TREE8_F4(K0,K1,K2,K3,K4,K5,K6,K7,DCQ)                                  \
    {                                                                          \
        float4 wgA = *(const float4*)&wws[(DCQ)];                              \
        float4 wgB = *(const float4*)&wws[(DCQ) + 4];                          \
        _Pragma("unroll")                                                      \
        for (int nn = 0; nn < 4; ++nn) {                                       \
            float4 egA = *(const float4*)&es[nn * 512 + (DCQ)];                \
            float4 egB = *(const float4*)&es[nn * 512 + (DCQ) + 4];            \
            f4v A0 = __builtin_elementwise_fma(K0,                             \
                     (f4v){egA.x, egA.x, egA.x, egA.x}, cc4);                  \
            f4v A1 = __builtin_elementwise_fma(K1,                             \
                     (f4v){egA.y, egA.y, egA.y, egA.y}, cc4);                  \
            f4v A2 = __builtin_elementwise_fma(K2,                             \
                     (f4v){egA.z, egA.z, egA.z, egA.z}, cc4);                  \
            f4v A3 = __builtin_elementwise_fma(K3,                             \
                     (f4v){egA.w, egA.w, egA.w, egA.w}, cc4);                  \
            f4v A4 = __builtin_elementwise_fma(K4,                             \
                     (f4v){egB.x, egB.x, egB.x, egB.x}, cc4);                  \
            f4v A5 = __builtin_elementwise_fma(K5,                             \
                     (f4v){egB.y, egB.y, egB.y, egB.y}, cc4);                  \
            f4v A6 = __builtin_elementwise_fma(K6,                             \
                     (f4v){egB.z, egB.z, egB.z, egB.z}, cc4);                  \
            f4v A7 = __builtin_elementwise_fma(K7,                             \
                     (f4v){egB.w, egB.w, egB.w, egB.w}, cc4);                  \
            f4v n01 = __builtin_elementwise_fma(                               \
                (f4v){wgA.y, wgA.y, wgA.y, wgA.y}, A0,                         \
                (f4v){wgA.x, wgA.x, wgA.x, wgA.x} * A1);                       \
            f4v d01 = A0 * A1;                                                 \
            f4v n23 = __builtin_elementwise_fma(                               \
                (f4v){wgA.w, wgA.w, wgA.w, wgA.w}, A2,                         \
                (f4v){wgA.z, wgA.z, wgA.z, wgA.z} * A3);                       \
            f4v d23 = A2 * A3;                                                 \
            f4v n45 = __builtin_elementwise_fma(                               \
                (f4v){wgB.y, wgB.y, wgB.y, wgB.y}, A4,                         \
                (f4v){wgB.x, wgB.x, wgB.x, wgB.x} * A5);                       \
            f4v d45 = A4 * A5;                                                 \
            f4v n67 = __builtin_elementwise_fma(                               \
                (f4v){wgB.w, wgB.w, wgB.w, wgB.w}, A6,                         \
                (f4v){wgB.z, wgB.z, wgB.z, wgB.z} * A7);                       \
            f4v d67 = A6 * A7;                                                 \
            f4v nA = __builtin_elementwise_fma(n01, d23, n23 * d01);           \
            f4v dA = d01 * d23;                                                \
            f4v nB = __builtin_elementwise_fma(n45, d67, n67 * d45);           \
            f4v dB = d45 * d67;                                                \
            f4v num = __builtin_elementwise_fma(nA, dB, nB * dA);              \
            f4v den = dA * dB;                                                 \
            f4v r = {__builtin_amdgcn_rcpf(den.x),                             \
                     __builtin_amdgcn_rcpf(den.y),                             \
                     __builtin_amdgcn_rcpf(den.z),                             \
                     __builtin_amdgcn_rcpf(den.w)};                            \
            acc[nn] = __builtin_elementwise_fma(num, r, acc[nn]);              \
        }                                                                      \
    }

__global__ __launch_bounds__(256) void score_kernel(const float* __restrict__ eq,
                                                    const float* __restrict__ ekT,
                                                    const float* __restrict__ Ww,
                                                    const int* __restrict__ mask,
                                                    ushort* __restrict__ Ph,
                                                    ushort* __restrict__ Pl,
                                                    float* __restrict__ rsum)
{
    __shared__ __align__(16) float es[4 * 512];       // 8 KB (pre-scaled eq)
    __shared__ __align__(16) float wws[512];          // 2 KB (scaled)
    __shared__ __align__(16) float red[2 * 16 * 64];  // 8 KB [mg][comp][lane]
    const int t    = threadIdx.x;
    const int lane = t & 63;
    const int w    = t >> 6;                 // 0..3
    const int mg   = w & 1;                  // m-group (256 cols)
    const int dh   = w >> 1;                 // d-half (256 rows)
    const int mw   = blockIdx.x * 512 + mg * 256;
    const int n0   = blockIdx.y * 4;
    const int db   = dh * 256;

    const float SC = 1.220703125e-4f;        // c = 2^-13

    // stage es: 4n x 512d = 512 float4-slots; 256 threads x 2
#pragma unroll
    for (int p = 0; p < 2; ++p) {
        int idx = t + p * 256;
        int nl = idx >> 7, c4 = idx & 127;
        *(float4*)&es[nl * 512 + c4 * 4] =
            *(const float4*)&eq[(size_t)(n0 + nl) * DDIM + c4 * 4];
    }
    wws[t]       = Ww[t] * SC;
    wws[t + 256] = Ww[t + 256] * SC;

    // per-lane global k stream over d-half [db, db+256); lane owns 4 m
    const float* gk = ekT + (size_t)db * MDIM + mw + lane * 4;

    f4v a0 = *(const f4v*)(gk + (size_t)0 * MDIM);
    f4v a1 = *(const f4v*)(gk + (size_t)1 * MDIM);
    f4v a2 = *(const f4v*)(gk + (size_t)2 * MDIM);
    f4v a3 = *(const f4v*)(gk + (size_t)3 * MDIM);
    f4v a4 = *(const f4v*)(gk + (size_t)4 * MDIM);
    f4v a5 = *(const f4v*)(gk + (size_t)5 * MDIM);
    f4v a6 = *(const f4v*)(gk + (size_t)6 * MDIM);
    f4v a7 = *(const f4v*)(gk + (size_t)7 * MDIM);

    __syncthreads();   // es/wws visible

    f4v acc[4] = {};
    const f4v cc4 = {1.220703125e-4f, 1.220703125e-4f,
                     1.220703125e-4f, 1.220703125e-4f};   // {c,c,c,c}

    for (int dc = 0; dc < 256; dc += 16) {
        const float* g8 = gk + (size_t)(dc + 8) * MDIM;
        f4v b0 = *(const f4v*)(g8 + (size_t)0 * MDIM);
        f4v b1 = *(const f4v*)(g8 + (size_t)1 * MDIM);
        f4v b2 = *(const f4v*)(g8 + (size_t)2 * MDIM);
        f4v b3 = *(const f4v*)(g8 + (size_t)3 * MDIM);
        f4v b4 = *(const f4v*)(g8 + (size_t)4 * MDIM);
        f4v b5 = *(const f4v*)(g8 + (size_t)5 * MDIM);
        f4v b6 = *(const f4v*)(g8 + (size_t)6 * MDIM);
        f4v b7 = *(const f4v*)(g8 + (size_t)7 * MDIM);

        TREE8_F4(a0, a1, a2, a3, a4, a5, a6, a7, db + dc)

        if (dc + 16 < 256) {
            const float* g16 = gk + (size_t)(dc + 16) * MDIM;
            a0 = *(const f4v*)(g16 + (size_t)0 * MDIM);
            a1 = *(const f4v*)(g16 + (size_t)1 * MDIM);
            a2 = *(const f4v*)(g16 + (size_t)2 * MDIM);
            a3 = *(const f4v*)(g16 + (size_t)3 * MDIM);
            a4 = *(const f4v*)(g16 + (size_t)4 * MDIM);
            a5 = *(const f4v*)(g16 + (size_t)5 * MDIM);
            a6 = *(const f4v*)(g16 + (size_t)6 * MDIM);
            a7 = *(const f4v*)(g16 + (size_t)7 * MDIM);
        }

        TREE8_F4(b0, b1, b2, b3, b4, b5, b6, b7, db + dc + 8)
    }

    // d-half reduction: dh=1 dumps (4B lane stride -> conflict-free)
    if (dh) {
        float* rb = &red[(mg * 16) * 64 + lane];
#pragma unroll
        for (int nn = 0; nn < 4; ++nn) {
            rb[(nn * 4 + 0) * 64] = acc[nn].x;
            rb[(nn * 4 + 1) * 64] = acc[nn].y;
            rb[(nn * 4 + 2) * 64] = acc[nn].z;
            rb[(nn * 4 + 3) * 64] = acc[nn].w;
        }
    }
    __syncthreads();
    if (!dh) {
        const float* rb = &red[(mg * 16) * 64 + lane];
#pragma unroll
        for (int nn = 0; nn < 4; ++nn) {
            acc[nn].x += rb[(nn * 4 + 0) * 64];
            acc[nn].y += rb[(nn * 4 + 1) * 64];
            acc[nn].z += rb[(nn * 4 + 2) * 64];
            acc[nn].w += rb[(nn * 4 + 3) * 64];
        }

        // fused softmax epilogue: mask + exp2 + bf16 h/l + row partials
        const float C2 = -2.8853900817779268f;   // -2*log2(e)
        const int m = mw + lane * 4;
        float rs[4];
#pragma unroll
        for (int nn = 0; nn < 4; ++nn) {
            int n = n0 + nn;
            int4 mk = *(const int4*)&mask[(size_t)n * MDIM + m];
            float p0 = mk.x ? __builtin_amdgcn_exp2f(acc[nn].x * C2) : 0.f;
            float p1 = mk.y ? __builtin_amdgcn_exp2f(acc[nn].y * C2) : 0.f;
            float p2 = mk.z ? __builtin_amdgcn_exp2f(acc[nn].z * C2) : 0.f;
            float p3 = mk.w ? __builtin_amdgcn_exp2f(acc[nn].w * C2) : 0.f;
            ushort2 h01, l01, h23, l23;
            hl2(p0, p1, h01, l01);
            hl2(p2, p3, h23, l23);
            ushort4 hv = {h01.x, h01.y, h23.x, h23.y};
            ushort4 lv = {l01.x, l01.y, l23.x, l23.y};
            *(ushort4*)&Ph[(size_t)n * MDIM + m] = hv;
            *(ushort4*)&Pl[(size_t)n * MDIM + m] = lv;
            rs[nn] = (p0 + p1) + (p2 + p3);
        }
#pragma unroll
        for (int off = 32; off; off >>= 1) {
            rs[0] += __shfl_xor(rs[0], off);
            rs[1] += __shfl_xor(rs[1], off);
            rs[2] += __shfl_xor(rs[2], off);
            rs[3] += __shfl_xor(rs[3], off);
        }
        if (lane == 0) {
#pragma unroll
            for (int nn = 0; nn < 4; ++nn)
                atomicAdd(&rsum[n0 + nn], rs[nn]);
        }
    }
}

// ---------------- K3: context MFMA (m-split x4 + LDS reduce) -----------------
// out[n][d] = (sum_m P[n][m]*vpT[d][m]) * rcp(rsum[n])
// grid (32,64) = 2048 blocks = 8/CU. Wave w sums m in [w*256,(w+1)*256);
// partials LDS-reduced by wave 0.
__global__ __launch_bounds__(256) void ctx_gemm(const ushort* __restrict__ Ph,
                                                const ushort* __restrict__ Pl,
                                                const ushort* __restrict__ vph,
                                                const ushort* __restrict__ vpl,
                                                const float* __restrict__ rsum,
                                                float* __restrict__ out)
{
    __shared__ __align__(16) float red[3 * 64 * 4];   // 3 KB
    const int t    = threadIdx.x;
    const int lane = t & 63;
    const int w    = t >> 6;
    const int lm   = lane & 15;
    const int lq   = lane >> 4;
    const int d0   = blockIdx.x * 16;
    const int n0   = blockIdx.y * 16;
    const int mb   = w * 256;

    const ushort* pAh = Ph  + (size_t)(n0 + lm) * MDIM + mb + lq * 8;
    const ushort* pAl = Pl  + (size_t)(n0 + lm) * MDIM + mb + lq * 8;
    const ushort* pBh = vph + (size_t)(d0 + lm) * MDIM + mb + lq * 8;
    const ushort* pBl = vpl + (size_t)(d0 + lm) * MDIM + mb + lq * 8;

    f4v acc = {0.f, 0.f, 0.f, 0.f};
#pragma unroll 4
    for (int m0 = 0; m0 < 256; m0 += 32) {
        s8v ah = *(const s8v*)(pAh + m0);
        s8v al = *(const s8v*)(pAl + m0);
        s8v bh = *(const s8v*)(pBh + m0);
        s8v bl = *(const s8v*)(pBl + m0);
        acc = __builtin_amdgcn_mfma_f32_16x16x32_bf16(ah, bh, acc, 0, 0, 0);
        acc = __builtin_amdgcn_mfma_f32_16x16x32_bf16(ah, bl, acc, 0, 0, 0);
        acc = __builtin_amdgcn_mfma_f32_16x16x32_bf16(al, bh, acc, 0, 0, 0);
    }

    if (w > 0) *(f4v*)&red[((w - 1) * 64 + lane) * 4] = acc;
    __syncthreads();
    if (w == 0) {
#pragma unroll
        for (int i = 0; i < 3; ++i)
            acc += *(const f4v*)&red[(i * 64 + lane) * 4];
#pragma unroll
        for (int p = 0; p < 4; ++p) {
            int nrow = n0 + lq * 4 + p;
            float inv = __builtin_amdgcn_rcpf(rsum[nrow]);
            out[(size_t)nrow * DDIM + d0 + lm] = acc[p] * inv;
        }
    }
}

extern "C" void kernel_launch(void* const* d_in, const int* in_sizes, int n_in,
                              void* d_out, int out_size, void* d_ws, size_t ws_size,
                              hipStream_t stream)
{
    const float* q    = (const float*)d_in[0];
    const float* k    = (const float*)d_in[1];
    const float* v    = (const float*)d_in[2];
    const int*   mask = (const int*)d_in[3];
    const float* Wq   = (const float*)d_in[4];
    const float* bq   = (const float*)d_in[5];
    const float* Wk   = (const float*)d_in[6];
    const float* bk   = (const float*)d_in[7];
    const float* Wv   = (const float*)d_in[8];
    const float* bv   = (const float*)d_in[9];
    const float* Ww   = (const float*)d_in[10];
    // d_in[11] (bw) cancels under softmax.

    float* ws    = (float*)d_ws;
    float* eq    = ws;                       // 512K floats [1024 n][512 d]
    float* ekT   = ws + 524288;              // 512K [512 d][1024 m]
    ushort* vph  = (ushort*)(ws + 1048576);  // 1M ushorts [512 d][1024 m]
    ushort* vpl  = (ushort*)(ws + 1310720);  // 1M ushorts
    ushort* Ph   = (ushort*)(ws + 1572864);  // 1M ushorts [1024 n][1024 m]
    ushort* Pl   = (ushort*)(ws + 2097152);  // 1M ushorts
    float* rsum  = ws + 2621440;             // 1K floats
    float* out   = (float*)d_out;

    const float CS = 2.8853900817779268f;    // 2*log2(e)

    proj_gemm<<<dim3(256, 1, 3), dim3(256), 0, stream>>>(q, k, v, Wq, bq, Wk, bk,
                                                         Wv, bv, eq, ekT,
                                                         vph, vpl, rsum, CS);
    score_kernel<<<dim3(2, 256), dim3(256), 0, stream>>>(eq, ekT, Ww, mask,
                                                         Ph, Pl, rsum);
    ctx_gemm<<<dim3(32, 64), dim3(256), 0, stream>>>(Ph, Pl, vph, vpl, rsum, out);
}